// Round 2
// baseline (910.668 us; speedup 1.0000x reference)
//
#include <hip/hip_runtime.h>

typedef __bf16 bf16_t;
typedef __bf16 bf16x8 __attribute__((ext_vector_type(8)));
typedef __bf16 bf16x4 __attribute__((ext_vector_type(4)));
typedef float f32x4 __attribute__((ext_vector_type(4)));

#define BM 128
#define BN 128
#define BK 32
#define BKP 40  // padded LDS row stride (elements): 80B = 5*16B, breaks pow2 bank stride

// ---------------- GEMM: C = A[M,K](bf16) * Bt[Ntot,K]^T (bf16), fp32 acc ----------------
// mode 0: outb[row*ldo + ocol + col] = bf16(relu(acc + bias1 + bias2))
// mode 1: outf[row*ldo + col]        = acc + bias1
// mode 2: outb[row*ldo + ocol + col] = bf16(acc + bias1)
__global__ __launch_bounds__(256) void gemm_k(
    const bf16_t* __restrict__ A, int lda, int M,
    const bf16_t* __restrict__ Bt, int K,
    const float* __restrict__ bias1, const float* __restrict__ bias2,
    int mode, bf16_t* __restrict__ outb, float* __restrict__ outf,
    int ldo, int ocol)
{
    __shared__ __align__(16) bf16_t As[BM * BKP];
    __shared__ __align__(16) bf16_t Bs[BN * BKP];
    const int tid  = threadIdx.x;
    const int m0   = blockIdx.x * BM;
    const int n0   = blockIdx.y * BN;
    const int wave = tid >> 6, lane = tid & 63;
    const int wr   = wave >> 1, wc = wave & 1;
    const int lm   = lane & 15, quad = lane >> 4;

    f32x4 acc[4][4] = {};

    for (int k0 = 0; k0 < K; k0 += BK) {
        __syncthreads();
        #pragma unroll
        for (int c = tid; c < 512; c += 256) {
            int row = c >> 2;
            int cc  = (c & 3) << 3;
            int gm  = m0 + row; if (gm >= M) gm = M - 1;  // clamp: stores are guarded
            *(uint4*)&As[row * BKP + cc] =
                *(const uint4*)(A + (size_t)gm * lda + k0 + cc);
        }
        #pragma unroll
        for (int c = tid; c < 512; c += 256) {
            int row = c >> 2;
            int cc  = (c & 3) << 3;
            *(uint4*)&Bs[row * BKP + cc] =
                *(const uint4*)(Bt + (size_t)(n0 + row) * K + k0 + cc);
        }
        __syncthreads();

        bf16x8 af[4], bfr[4];
        #pragma unroll
        for (int i = 0; i < 4; i++)
            af[i] = *(const bf16x8*)&As[(wr * 64 + i * 16 + lm) * BKP + quad * 8];
        #pragma unroll
        for (int i = 0; i < 4; i++)
            bfr[i] = *(const bf16x8*)&Bs[(wc * 64 + i * 16 + lm) * BKP + quad * 8];
        #pragma unroll
        for (int mi = 0; mi < 4; mi++)
            #pragma unroll
            for (int ni = 0; ni < 4; ni++)
                acc[mi][ni] = __builtin_amdgcn_mfma_f32_16x16x32_bf16(
                    af[mi], bfr[ni], acc[mi][ni], 0, 0, 0);
    }

    // epilogue: C/D layout col=lane&15, row=quad*4+r
    #pragma unroll
    for (int mi = 0; mi < 4; mi++) {
        #pragma unroll
        for (int ni = 0; ni < 4; ni++) {
            int col = n0 + wc * 64 + ni * 16 + lm;
            float b = bias1[col];
            if (bias2) b += bias2[col];
            #pragma unroll
            for (int r = 0; r < 4; r++) {
                int row = m0 + wr * 64 + mi * 16 + quad * 4 + r;
                if (row < M) {
                    float v = acc[mi][ni][r] + b;
                    if (mode == 1) {
                        outf[(size_t)row * ldo + col] = v;
                    } else {
                        if (mode == 0) v = fmaxf(v, 0.f);
                        outb[(size_t)row * ldo + ocol + col] = (bf16_t)v;
                    }
                }
            }
        }
    }
}

// ---------------- CSR build ----------------
__global__ void count_k(const int* __restrict__ dst, const int* __restrict__ rel,
                        int* __restrict__ cnt, int E)
{
    int e = blockIdx.x * blockDim.x + threadIdx.x;
    if (e < E) atomicAdd(&cnt[dst[e] * 4 + rel[e]], 1);
}

// phase 1: per-256-chunk exclusive scan of cnt -> offs (block-local), chunk totals
__global__ void scan_partial(const int* __restrict__ cnt, int* __restrict__ offs,
                             int* __restrict__ chunkSums, int NSEG)
{
    __shared__ int sh[256];
    int t = threadIdx.x;
    int idx = blockIdx.x * 256 + t;
    int v = (idx < NSEG) ? cnt[idx] : 0;
    sh[t] = v;
    __syncthreads();
    for (int d = 1; d < 256; d <<= 1) {
        int add = (t >= d) ? sh[t - d] : 0;
        __syncthreads();
        sh[t] += add;
        __syncthreads();
    }
    if (idx < NSEG) offs[idx] = sh[t] - v;   // exclusive, block-local
    if (t == 255) chunkSums[blockIdx.x] = sh[t];
}

// phase 2: sequential exclusive scan of chunk totals (NCHUNK ~782)
__global__ void scan_chunks(int* __restrict__ chunkSums, int NCHUNK)
{
    if (threadIdx.x == 0 && blockIdx.x == 0) {
        int run = 0;
        for (int i = 0; i < NCHUNK; i++) {
            int t = chunkSums[i];
            chunkSums[i] = run;
            run += t;
        }
    }
}

// phase 3: add chunk base; init cursor
__global__ void scan_add(int* __restrict__ offs, const int* __restrict__ chunkSums,
                         int* __restrict__ cursor, int NSEG)
{
    int idx = blockIdx.x * 256 + threadIdx.x;
    if (idx < NSEG) {
        int o = offs[idx] + chunkSums[blockIdx.x];
        offs[idx] = o;
        cursor[idx] = o;
    }
}

__global__ void fill_k(const int* __restrict__ src, const int* __restrict__ dst,
                       const int* __restrict__ rel,
                       int* __restrict__ cursor, int* __restrict__ eidx, int E)
{
    int e = blockIdx.x * blockDim.x + threadIdx.x;
    if (e < E) {
        int seg = dst[e] * 4 + rel[e];
        int pos = atomicAdd(&cursor[seg], 1);
        eidx[pos] = src[e];
    }
}

// ---------------- segment mean: one wave per (node, relation) segment ----------------
// Aout[node*lda + r*D + c] = bf16( mean over edges of xb[src*ldx + c] )
__global__ void seg_mean(const int* __restrict__ offs, const int* __restrict__ cnt,
                         const int* __restrict__ eidx,
                         const bf16_t* __restrict__ xb, int ldx, int D,
                         bf16_t* __restrict__ Aout, int lda, int NSEG)
{
    int wv = (blockIdx.x << 2) + (threadIdx.x >> 6);
    if (wv >= NSEG) return;
    int lane = threadIdx.x & 63;
    int c = lane << 2;
    bool active = c < D;
    int start = offs[wv];
    int n = cnt[wv];
    f32x4 acc = {};
    for (int i = 0; i < n; i++) {
        int s = eidx[start + i];
        if (active) {
            bf16x4 v = *(const bf16x4*)(xb + (size_t)s * ldx + c);
            acc[0] += (float)v[0];
            acc[1] += (float)v[1];
            acc[2] += (float)v[2];
            acc[3] += (float)v[3];
        }
    }
    if (active) {
        float inv = 1.0f / ((float)n + 1e-10f);
        int node = wv >> 2, r = wv & 3;
        bf16x4 o;
        o[0] = (bf16_t)(acc[0] * inv);
        o[1] = (bf16_t)(acc[1] * inv);
        o[2] = (bf16_t)(acc[2] * inv);
        o[3] = (bf16_t)(acc[3] * inv);
        *(bf16x4*)(Aout + (size_t)node * lda + r * D + c) = o;
    }
}

// x fp32 [N,128] -> bf16 into A1 columns 512..640 (ld 640)
__global__ void convert_x_k(const float* __restrict__ x, bf16_t* __restrict__ A1, int N)
{
    int t = blockIdx.x * blockDim.x + threadIdx.x;
    if (t >= N * 32) return;
    int row = t >> 5;
    int c = (t & 31) << 2;
    f32x4 v = *(const f32x4*)(x + (size_t)row * 128 + c);
    bf16x4 o;
    o[0] = (bf16_t)v[0]; o[1] = (bf16_t)v[1]; o[2] = (bf16_t)v[2]; o[3] = (bf16_t)v[3];
    *(bf16x4*)(A1 + (size_t)row * 640 + 512 + c) = o;
}

// Wt[n, k0+k] = (bf16) W[k, n];  W is [K,256] row-major
__global__ void transpose_w(const float* __restrict__ W, bf16_t* __restrict__ Wt,
                            int K, int ldk, int k0)
{
    int t = blockIdx.x * blockDim.x + threadIdx.x;
    if (t >= K * 256) return;
    int k = t >> 8, n = t & 255;
    Wt[(size_t)n * ldk + k0 + k] = (bf16_t)W[(size_t)k * 256 + n];
}

// h' = sigmoid(G)*relu(P) + (1-sigmoid(G))*h ;  P,G bf16, bias already added
__global__ void highway_k(const bf16_t* __restrict__ P, const bf16_t* __restrict__ G,
                          const bf16_t* __restrict__ h, int N,
                          bf16_t* __restrict__ outb, int ldo, int ocol,
                          float* __restrict__ outf)
{
    int t = blockIdx.x * blockDim.x + threadIdx.x;
    if (t >= N * 64) return;
    int row = t >> 6;
    int c = (t & 63) << 2;
    size_t i = (size_t)row * 256 + c;
    bf16x4 p = *(const bf16x4*)(P + i);
    bf16x4 g = *(const bf16x4*)(G + i);
    bf16x4 hv = *(const bf16x4*)(h + i);
    bf16x4 ob;
    f32x4 of;
    #pragma unroll
    for (int j = 0; j < 4; j++) {
        float gg = 1.0f / (1.0f + __expf(-(float)g[j]));
        float pp = fmaxf((float)p[j], 0.f);
        float v = gg * pp + (1.0f - gg) * (float)hv[j];
        ob[j] = (bf16_t)v;
        of[j] = v;
    }
    if (outb) *(bf16x4*)(outb + (size_t)row * ldo + ocol + c) = ob;
    if (outf) *(f32x4*)(outf + i) = of;
}

extern "C" void kernel_launch(void* const* d_in, const int* in_sizes, int n_in,
                              void* d_out, int out_size, void* d_ws, size_t ws_size,
                              hipStream_t stream)
{
    const float* x       = (const float*)d_in[0];
    const int*   src     = (const int*)d_in[1];
    const int*   dst     = (const int*)d_in[2];
    const int*   rel     = (const int*)d_in[3];
    const float* rel_w1  = (const float*)d_in[4];
    const float* rel_b1  = (const float*)d_in[5];
    const float* loop_w1 = (const float*)d_in[6];
    const float* loop_b1 = (const float*)d_in[7];
    const float* hp_w1   = (const float*)d_in[8];
    const float* hp_b1   = (const float*)d_in[9];
    const float* ht_w1   = (const float*)d_in[10];
    const float* ht_b1   = (const float*)d_in[11];
    const float* rel_w2  = (const float*)d_in[12];
    const float* rel_b2  = (const float*)d_in[13];
    const float* loop_w2 = (const float*)d_in[14];
    const float* loop_b2 = (const float*)d_in[15];
    const float* hp_w2   = (const float*)d_in[16];
    const float* hp_b2   = (const float*)d_in[17];
    const float* ht_w2   = (const float*)d_in[18];
    const float* ht_b2   = (const float*)d_in[19];

    const int N = in_sizes[0] / 128;   // 50000
    const int E = in_sizes[1];         // 800000
    const int NSEG = N * 4;            // 200000
    const int NCHUNK = (NSEG + 255) / 256;
    float* out = (float*)d_out;

    // ---- workspace carve-up (~225 MB total) ----
    char* ws = (char*)d_ws;
    size_t off = 0;
    auto alloc = [&](size_t bytes) {
        void* p = ws + off;
        off += (bytes + 255) & ~(size_t)255;
        return p;
    };
    int*    cnt    = (int*)alloc((size_t)NSEG * 4);
    int*    offs   = (int*)alloc((size_t)NSEG * 4);
    int*    cursor = (int*)alloc((size_t)NSEG * 4);
    int*    chunkS = (int*)alloc(4096);
    int*    eidx   = (int*)alloc((size_t)E * 4);
    bf16_t* A1     = (bf16_t*)alloc((size_t)N * 640 * 2);    // [update1 | x_bf16]; after L1 GEMM hosts Pb|Gb
    bf16_t* A2     = (bf16_t*)alloc((size_t)N * 1280 * 2);   // [update2 | h1']
    bf16_t* h      = (bf16_t*)alloc((size_t)N * 256 * 2);
    bf16_t* W1t    = (bf16_t*)alloc((size_t)256 * 640 * 2);
    bf16_t* W2t    = (bf16_t*)alloc((size_t)256 * 1280 * 2);
    bf16_t* hp1t   = (bf16_t*)alloc((size_t)256 * 256 * 2);
    bf16_t* ht1t   = (bf16_t*)alloc((size_t)256 * 256 * 2);
    bf16_t* hp2t   = (bf16_t*)alloc((size_t)256 * 256 * 2);
    bf16_t* ht2t   = (bf16_t*)alloc((size_t)256 * 256 * 2);
    // P/G aliased into A1 (dead after layer-1 RGC GEMM)
    bf16_t* Pb = A1;
    bf16_t* Gb = A1 + (size_t)N * 256;

    dim3 blk(256);
    const int mtiles = (N + BM - 1) / BM;    // 391

    // ---- weight prep ----
    transpose_w<<<dim3(512), blk, 0, stream>>>(rel_w1, W1t, 512, 640, 0);
    transpose_w<<<dim3(128), blk, 0, stream>>>(loop_w1, W1t, 128, 640, 512);
    transpose_w<<<dim3(1024), blk, 0, stream>>>(rel_w2, W2t, 1024, 1280, 0);
    transpose_w<<<dim3(256), blk, 0, stream>>>(loop_w2, W2t, 256, 1280, 1024);
    transpose_w<<<dim3(256), blk, 0, stream>>>(hp_w1, hp1t, 256, 256, 0);
    transpose_w<<<dim3(256), blk, 0, stream>>>(ht_w1, ht1t, 256, 256, 0);
    transpose_w<<<dim3(256), blk, 0, stream>>>(hp_w2, hp2t, 256, 256, 0);
    transpose_w<<<dim3(256), blk, 0, stream>>>(ht_w2, ht2t, 256, 256, 0);
    convert_x_k<<<dim3((N * 32 + 255) / 256), blk, 0, stream>>>(x, A1, N);

    // ---- CSR build (shared by both layers) ----
    hipMemsetAsync(cnt, 0, (size_t)NSEG * 4, stream);
    count_k<<<dim3((E + 255) / 256), blk, 0, stream>>>(dst, rel, cnt, E);
    scan_partial<<<dim3(NCHUNK), blk, 0, stream>>>(cnt, offs, chunkS, NSEG);
    scan_chunks<<<dim3(1), dim3(64), 0, stream>>>(chunkS, NCHUNK);
    scan_add<<<dim3(NCHUNK), blk, 0, stream>>>(offs, chunkS, cursor, NSEG);
    fill_k<<<dim3((E + 255) / 256), blk, 0, stream>>>(src, dst, rel, cursor, eidx, E);

    // ---- layer 1: segment mean (D=128) from bf16 x (A1 cols 512..640) ----
    seg_mean<<<dim3((NSEG + 3) / 4), blk, 0, stream>>>(offs, cnt, eidx,
                                                       A1 + 512, 640, 128, A1, 640, NSEG);
    // ---- layer 1: RGC GEMM (K=640) -> h1 = relu ----
    gemm_k<<<dim3(mtiles, 2), blk, 0, stream>>>(A1, 640, N, W1t, 640,
                                                rel_b1, loop_b1, 0, h, nullptr, 256, 0);
    // ---- highway 1 (A1 now dead; Pb/Gb alias it) ----
    gemm_k<<<dim3(mtiles, 2), blk, 0, stream>>>(h, 256, N, hp1t, 256,
                                                hp_b1, nullptr, 2, Pb, nullptr, 256, 0);
    gemm_k<<<dim3(mtiles, 2), blk, 0, stream>>>(h, 256, N, ht1t, 256,
                                                ht_b1, nullptr, 2, Gb, nullptr, 256, 0);
    highway_k<<<dim3((N * 64 + 255) / 256), blk, 0, stream>>>(Pb, Gb, h, N,
                                                              A2, 1280, 1024, nullptr);

    // ---- layer 2: segment mean (D=256) from h1' (A2 cols 1024..1280) ----
    seg_mean<<<dim3((NSEG + 3) / 4), blk, 0, stream>>>(offs, cnt, eidx,
                                                       A2 + 1024, 1280, 256, A2, 1280, NSEG);
    // ---- layer 2: RGC GEMM (K=1280) -> h2 ----
    gemm_k<<<dim3(mtiles, 2), blk, 0, stream>>>(A2, 1280, N, W2t, 1280,
                                                rel_b2, loop_b2, 0, h, nullptr, 256, 0);
    // ---- highway 2 -> d_out (fp32) ----
    gemm_k<<<dim3(mtiles, 2), blk, 0, stream>>>(h, 256, N, hp2t, 256,
                                                hp_b2, nullptr, 2, Pb, nullptr, 256, 0);
    gemm_k<<<dim3(mtiles, 2), blk, 0, stream>>>(h, 256, N, ht2t, 256,
                                                ht_b2, nullptr, 2, Gb, nullptr, 256, 0);
    highway_k<<<dim3((N * 64 + 255) / 256), blk, 0, stream>>>(Pb, Gb, h, N,
                                                              nullptr, 0, 0, out);
}

// Round 3
// 706.531 us; speedup vs baseline: 1.2889x; 1.2889x over previous
//
#include <hip/hip_runtime.h>

typedef __bf16 bf16_t;
typedef __bf16 bf16x8 __attribute__((ext_vector_type(8)));
typedef __bf16 bf16x4 __attribute__((ext_vector_type(4)));
typedef float f32x4 __attribute__((ext_vector_type(4)));

#define BM 128
#define BN 128
#define BK 32
// NOTE: LDS tiles are UNPADDED [row][32] — global_load_lds DMA writes
// base + lane*16 contiguously; padding would corrupt the layout (m104/m108).

__device__ __forceinline__ void gload_lds16(const void* g, void* s) {
    __builtin_amdgcn_global_load_lds(
        (const __attribute__((address_space(1))) unsigned int*)g,
        (__attribute__((address_space(3))) unsigned int*)s, 16, 0, 0);
}

// ---------------- GEMM: C = A[M,K](bf16) * Bt[Ntot,K]^T (bf16), fp32 acc ----------------
// relu_flag 1: outb[row*ldo + ocol + col] = bf16(relu(acc + bias[col]))
// relu_flag 0: outb[row*ldo + ocol + col] = bf16(acc + bias[col])
__global__ __launch_bounds__(256) void gemm_k(
    const bf16_t* __restrict__ A, int lda, int M,
    const bf16_t* __restrict__ Bt, int K,
    const float* __restrict__ bias, int relu_flag,
    bf16_t* __restrict__ outb, int ldo, int ocol)
{
    __shared__ __align__(16) bf16_t As[BM * BK];   // 8 KB
    __shared__ __align__(16) bf16_t Bs[BN * BK];   // 8 KB
    const int tid  = threadIdx.x;
    const int m0   = blockIdx.x * BM;
    const int n0   = blockIdx.y * BN;
    const int wave = tid >> 6, lane = tid & 63;
    const int wr   = wave >> 1, wc = wave & 1;
    const int lm   = lane & 15, quad = lane >> 4;

    f32x4 acc[4][4] = {};

    for (int k0 = 0; k0 < K; k0 += BK) {
        __syncthreads();   // previous tile's reads complete
        // stage A: 512 chunks of 16B; wave w, call j covers chunks w*128+j*64+lane
        #pragma unroll
        for (int j = 0; j < 2; j++) {
            int c   = wave * 128 + j * 64 + lane;
            int row = c >> 2;
            int col = (c & 3) << 3;
            int gm  = m0 + row; if (gm >= M) gm = M - 1;   // clamp; stores guarded
            gload_lds16(A + (size_t)gm * lda + k0 + col,
                        As + (size_t)(wave * 128 + j * 64) * 8);
        }
        // stage B (rows n0..n0+127 always in-bounds by grid construction)
        #pragma unroll
        for (int j = 0; j < 2; j++) {
            int c   = wave * 128 + j * 64 + lane;
            int row = c >> 2;
            int col = (c & 3) << 3;
            gload_lds16(Bt + (size_t)(n0 + row) * K + k0 + col,
                        Bs + (size_t)(wave * 128 + j * 64) * 8);
        }
        __syncthreads();   // DMA drained (compiler emits vmcnt(0) before barrier)

        bf16x8 af[4], bfr[4];
        #pragma unroll
        for (int i = 0; i < 4; i++)
            af[i] = *(const bf16x8*)&As[(wr * 64 + i * 16 + lm) * BK + quad * 8];
        #pragma unroll
        for (int i = 0; i < 4; i++)
            bfr[i] = *(const bf16x8*)&Bs[(wc * 64 + i * 16 + lm) * BK + quad * 8];
        #pragma unroll
        for (int mi = 0; mi < 4; mi++)
            #pragma unroll
            for (int ni = 0; ni < 4; ni++)
                acc[mi][ni] = __builtin_amdgcn_mfma_f32_16x16x32_bf16(
                    af[mi], bfr[ni], acc[mi][ni], 0, 0, 0);
    }

    // epilogue: C/D layout col=lane&15, row=quad*4+r
    #pragma unroll
    for (int mi = 0; mi < 4; mi++) {
        #pragma unroll
        for (int ni = 0; ni < 4; ni++) {
            int col = n0 + wc * 64 + ni * 16 + lm;
            float b = bias[col];
            #pragma unroll
            for (int r = 0; r < 4; r++) {
                int row = m0 + wr * 64 + mi * 16 + quad * 4 + r;
                if (row < M) {
                    float v = acc[mi][ni][r] + b;
                    if (relu_flag) v = fmaxf(v, 0.f);
                    outb[(size_t)row * ldo + ocol + col] = (bf16_t)v;
                }
            }
        }
    }
}

// ---------------- CSR build ----------------
__global__ void count_k(const int* __restrict__ dst, const int* __restrict__ rel,
                        int* __restrict__ cnt, int E)
{
    int e = blockIdx.x * blockDim.x + threadIdx.x;
    if (e < E) atomicAdd(&cnt[dst[e] * 4 + rel[e]], 1);
}

__global__ void scan_partial(const int* __restrict__ cnt, int* __restrict__ offs,
                             int* __restrict__ chunkSums, int NSEG)
{
    __shared__ int sh[256];
    int t = threadIdx.x;
    int idx = blockIdx.x * 256 + t;
    int v = (idx < NSEG) ? cnt[idx] : 0;
    sh[t] = v;
    __syncthreads();
    for (int d = 1; d < 256; d <<= 1) {
        int add = (t >= d) ? sh[t - d] : 0;
        __syncthreads();
        sh[t] += add;
        __syncthreads();
    }
    if (idx < NSEG) offs[idx] = sh[t] - v;   // exclusive, block-local
    if (t == 255) chunkSums[blockIdx.x] = sh[t];
}

// parallel exclusive scan of chunk totals (NCHUNK <= 1024); 1 block x 1024 thr
__global__ void scan_chunks(int* __restrict__ chunkSums, int NCHUNK)
{
    __shared__ int sh[1024];
    int t = threadIdx.x;
    int v = (t < NCHUNK) ? chunkSums[t] : 0;
    sh[t] = v;
    __syncthreads();
    for (int d = 1; d < 1024; d <<= 1) {
        int add = (t >= d) ? sh[t - d] : 0;
        __syncthreads();
        sh[t] += add;
        __syncthreads();
    }
    if (t < NCHUNK) chunkSums[t] = sh[t] - v;   // exclusive
}

__global__ void scan_add(int* __restrict__ offs, const int* __restrict__ chunkSums,
                         int* __restrict__ cursor, int NSEG)
{
    int idx = blockIdx.x * 256 + threadIdx.x;
    if (idx < NSEG) {
        int o = offs[idx] + chunkSums[blockIdx.x];
        offs[idx] = o;
        cursor[idx] = o;
    }
}

__global__ void fill_k(const int* __restrict__ src, const int* __restrict__ dst,
                       const int* __restrict__ rel,
                       int* __restrict__ cursor, int* __restrict__ eidx, int E)
{
    int e = blockIdx.x * blockDim.x + threadIdx.x;
    if (e < E) {
        int seg = dst[e] * 4 + rel[e];
        int pos = atomicAdd(&cursor[seg], 1);
        eidx[pos] = src[e];
    }
}

// ---------------- segment mean: one wave per (node, relation) segment ----------------
__global__ void seg_mean(const int* __restrict__ offs, const int* __restrict__ cnt,
                         const int* __restrict__ eidx,
                         const bf16_t* __restrict__ xb, int ldx, int D,
                         bf16_t* __restrict__ Aout, int lda, int NSEG)
{
    int wv = (blockIdx.x << 2) + (threadIdx.x >> 6);
    if (wv >= NSEG) return;
    int lane = threadIdx.x & 63;
    int c = lane << 2;
    bool active = c < D;
    int start = offs[wv];
    int n = cnt[wv];
    f32x4 acc = {};
    for (int i = 0; i < n; i++) {
        int s = eidx[start + i];
        if (active) {
            bf16x4 v = *(const bf16x4*)(xb + (size_t)s * ldx + c);
            acc[0] += (float)v[0];
            acc[1] += (float)v[1];
            acc[2] += (float)v[2];
            acc[3] += (float)v[3];
        }
    }
    if (active) {
        float inv = 1.0f / ((float)n + 1e-10f);
        int node = wv >> 2, r = wv & 3;
        bf16x4 o;
        o[0] = (bf16_t)(acc[0] * inv);
        o[1] = (bf16_t)(acc[1] * inv);
        o[2] = (bf16_t)(acc[2] * inv);
        o[3] = (bf16_t)(acc[3] * inv);
        *(bf16x4*)(Aout + (size_t)node * lda + r * D + c) = o;
    }
}

// x fp32 [N,128] -> bf16 into A1 columns 512..640 (ld 640)
__global__ void convert_x_k(const float* __restrict__ x, bf16_t* __restrict__ A1, int N)
{
    int t = blockIdx.x * blockDim.x + threadIdx.x;
    if (t >= N * 32) return;
    int row = t >> 5;
    int c = (t & 31) << 2;
    f32x4 v = *(const f32x4*)(x + (size_t)row * 128 + c);
    bf16x4 o;
    o[0] = (bf16_t)v[0]; o[1] = (bf16_t)v[1]; o[2] = (bf16_t)v[2]; o[3] = (bf16_t)v[3];
    *(bf16x4*)(A1 + (size_t)row * 640 + 512 + c) = o;
}

// Wt[(n0+n)*ldk + k0 + k] = (bf16) W[k, n];  W is [K,256] row-major
__global__ void transpose_w(const float* __restrict__ W, bf16_t* __restrict__ Wt,
                            int K, int ldk, int k0, int n0)
{
    int t = blockIdx.x * blockDim.x + threadIdx.x;
    if (t >= K * 256) return;
    int k = t >> 8, n = t & 255;
    Wt[(size_t)(n0 + n) * ldk + k0 + k] = (bf16_t)W[(size_t)k * 256 + n];
}

// bias prep: bR = rel_b + loop_b (per layer); bH = [hp_b | ht_b] (per layer)
__global__ void prep_bias(const float* rb1, const float* lb1,
                          const float* rb2, const float* lb2,
                          const float* hpb1, const float* htb1,
                          const float* hpb2, const float* htb2,
                          float* bR1, float* bR2, float* bH1, float* bH2)
{
    int t = threadIdx.x;  // 256
    bR1[t] = rb1[t] + lb1[t];
    bR2[t] = rb2[t] + lb2[t];
    bH1[t] = hpb1[t]; bH1[256 + t] = htb1[t];
    bH2[t] = hpb2[t]; bH2[256 + t] = htb2[t];
}

// h' = sigmoid(G)*relu(P) + (1-sigmoid(G))*h ;  PG = [P | G] bf16 [N,512]
__global__ void highway_k(const bf16_t* __restrict__ PG, const bf16_t* __restrict__ h,
                          int N, bf16_t* __restrict__ outb, int ldo, int ocol,
                          float* __restrict__ outf)
{
    int t = blockIdx.x * blockDim.x + threadIdx.x;
    if (t >= N * 64) return;
    int row = t >> 6;
    int c = (t & 63) << 2;
    size_t ip = (size_t)row * 512 + c;
    bf16x4 p = *(const bf16x4*)(PG + ip);
    bf16x4 g = *(const bf16x4*)(PG + ip + 256);
    bf16x4 hv = *(const bf16x4*)(h + (size_t)row * 256 + c);
    bf16x4 ob;
    f32x4 of;
    #pragma unroll
    for (int j = 0; j < 4; j++) {
        float gg = 1.0f / (1.0f + __expf(-(float)g[j]));
        float pp = fmaxf((float)p[j], 0.f);
        float v = gg * pp + (1.0f - gg) * (float)hv[j];
        ob[j] = (bf16_t)v;
        of[j] = v;
    }
    if (outb) *(bf16x4*)(outb + (size_t)row * ldo + ocol + c) = ob;
    if (outf) *(f32x4*)(outf + (size_t)row * 256 + c) = of;
}

extern "C" void kernel_launch(void* const* d_in, const int* in_sizes, int n_in,
                              void* d_out, int out_size, void* d_ws, size_t ws_size,
                              hipStream_t stream)
{
    const float* x       = (const float*)d_in[0];
    const int*   src     = (const int*)d_in[1];
    const int*   dst     = (const int*)d_in[2];
    const int*   rel     = (const int*)d_in[3];
    const float* rel_w1  = (const float*)d_in[4];
    const float* rel_b1  = (const float*)d_in[5];
    const float* loop_w1 = (const float*)d_in[6];
    const float* loop_b1 = (const float*)d_in[7];
    const float* hp_w1   = (const float*)d_in[8];
    const float* hp_b1   = (const float*)d_in[9];
    const float* ht_w1   = (const float*)d_in[10];
    const float* ht_b1   = (const float*)d_in[11];
    const float* rel_w2  = (const float*)d_in[12];
    const float* rel_b2  = (const float*)d_in[13];
    const float* loop_w2 = (const float*)d_in[14];
    const float* loop_b2 = (const float*)d_in[15];
    const float* hp_w2   = (const float*)d_in[16];
    const float* hp_b2   = (const float*)d_in[17];
    const float* ht_w2   = (const float*)d_in[18];
    const float* ht_b2   = (const float*)d_in[19];

    const int N = in_sizes[0] / 128;   // 50000
    const int E = in_sizes[1];         // 800000
    const int NSEG = N * 4;            // 200000
    const int NCHUNK = (NSEG + 255) / 256;   // 782 (<=1024 required by scan_chunks)
    float* out = (float*)d_out;

    // ---- workspace carve-up (~224 MB total) ----
    char* ws = (char*)d_ws;
    size_t off = 0;
    auto alloc = [&](size_t bytes) {
        void* p = ws + off;
        off += (bytes + 255) & ~(size_t)255;
        return p;
    };
    int*    cnt    = (int*)alloc((size_t)NSEG * 4);
    int*    offs   = (int*)alloc((size_t)NSEG * 4);
    int*    cursor = (int*)alloc((size_t)NSEG * 4);
    int*    chunkS = (int*)alloc(4096);
    int*    eidx   = (int*)alloc((size_t)E * 4);
    bf16_t* A1     = (bf16_t*)alloc((size_t)N * 640 * 2);    // [update1 | x_bf16]; later hosts PG
    bf16_t* A2     = (bf16_t*)alloc((size_t)N * 1280 * 2);   // [update2 | h1']
    bf16_t* h      = (bf16_t*)alloc((size_t)N * 256 * 2);
    bf16_t* W1t    = (bf16_t*)alloc((size_t)256 * 640 * 2);
    bf16_t* W2t    = (bf16_t*)alloc((size_t)256 * 1280 * 2);
    bf16_t* Wh1t   = (bf16_t*)alloc((size_t)512 * 256 * 2);  // [hp ; ht] concat over N
    bf16_t* Wh2t   = (bf16_t*)alloc((size_t)512 * 256 * 2);
    float*  bR1    = (float*)alloc(256 * 4);
    float*  bR2    = (float*)alloc(256 * 4);
    float*  bH1    = (float*)alloc(512 * 4);
    float*  bH2    = (float*)alloc(512 * 4);
    bf16_t* PG     = A1;   // alias: A1 dead after layer-1 RGC GEMM; reused both layers

    dim3 blk(256);
    const int mtiles = (N + BM - 1) / BM;    // 391

    // ---- weight/bias prep ----
    transpose_w<<<dim3(512), blk, 0, stream>>>(rel_w1, W1t, 512, 640, 0, 0);
    transpose_w<<<dim3(128), blk, 0, stream>>>(loop_w1, W1t, 128, 640, 512, 0);
    transpose_w<<<dim3(1024), blk, 0, stream>>>(rel_w2, W2t, 1024, 1280, 0, 0);
    transpose_w<<<dim3(256), blk, 0, stream>>>(loop_w2, W2t, 256, 1280, 1024, 0);
    transpose_w<<<dim3(256), blk, 0, stream>>>(hp_w1, Wh1t, 256, 256, 0, 0);
    transpose_w<<<dim3(256), blk, 0, stream>>>(ht_w1, Wh1t, 256, 256, 0, 256);
    transpose_w<<<dim3(256), blk, 0, stream>>>(hp_w2, Wh2t, 256, 256, 0, 0);
    transpose_w<<<dim3(256), blk, 0, stream>>>(ht_w2, Wh2t, 256, 256, 0, 256);
    prep_bias<<<dim3(1), blk, 0, stream>>>(rel_b1, loop_b1, rel_b2, loop_b2,
                                           hp_b1, ht_b1, hp_b2, ht_b2,
                                           bR1, bR2, bH1, bH2);
    convert_x_k<<<dim3((N * 32 + 255) / 256), blk, 0, stream>>>(x, A1, N);

    // ---- CSR build (shared by both layers) ----
    hipMemsetAsync(cnt, 0, (size_t)NSEG * 4, stream);
    count_k<<<dim3((E + 255) / 256), blk, 0, stream>>>(dst, rel, cnt, E);
    scan_partial<<<dim3(NCHUNK), blk, 0, stream>>>(cnt, offs, chunkS, NSEG);
    scan_chunks<<<dim3(1), dim3(1024), 0, stream>>>(chunkS, NCHUNK);
    scan_add<<<dim3(NCHUNK), blk, 0, stream>>>(offs, chunkS, cursor, NSEG);
    fill_k<<<dim3((E + 255) / 256), blk, 0, stream>>>(src, dst, rel, cursor, eidx, E);

    // ---- layer 1 ----
    seg_mean<<<dim3((NSEG + 3) / 4), blk, 0, stream>>>(offs, cnt, eidx,
                                                       A1 + 512, 640, 128, A1, 640, NSEG);
    gemm_k<<<dim3(mtiles, 2), blk, 0, stream>>>(A1, 640, N, W1t, 640,
                                                bR1, 1, h, 256, 0);
    gemm_k<<<dim3(mtiles, 4), blk, 0, stream>>>(h, 256, N, Wh1t, 256,
                                                bH1, 0, PG, 512, 0);
    highway_k<<<dim3((N * 64 + 255) / 256), blk, 0, stream>>>(PG, h, N,
                                                              A2, 1280, 1024, nullptr);

    // ---- layer 2 ----
    seg_mean<<<dim3((NSEG + 3) / 4), blk, 0, stream>>>(offs, cnt, eidx,
                                                       A2 + 1024, 1280, 256, A2, 1280, NSEG);
    gemm_k<<<dim3(mtiles, 2), blk, 0, stream>>>(A2, 1280, N, W2t, 1280,
                                                bR2, 1, h, 256, 0);
    gemm_k<<<dim3(mtiles, 4), blk, 0, stream>>>(h, 256, N, Wh2t, 256,
                                                bH2, 0, PG, 512, 0);
    highway_k<<<dim3((N * 64 + 255) / 256), blk, 0, stream>>>(PG, h, N,
                                                              nullptr, 0, 0, out);
}

// Round 4
// 616.467 us; speedup vs baseline: 1.4772x; 1.1461x over previous
//
#include <hip/hip_runtime.h>

typedef __bf16 bf16_t;
typedef __bf16 bf16x8 __attribute__((ext_vector_type(8)));
typedef __bf16 bf16x4 __attribute__((ext_vector_type(4)));
typedef float f32x4 __attribute__((ext_vector_type(4)));

#define BM 128
#define BN 128
#define BK 32
// NOTE: LDS tiles are UNPADDED [row][32] — global_load_lds DMA writes
// base + lane*16 contiguously; padding would corrupt the layout (m104/m108).

__device__ __forceinline__ void gload_lds16(const void* g, void* s) {
    __builtin_amdgcn_global_load_lds(
        (const __attribute__((address_space(1))) unsigned int*)g,
        (__attribute__((address_space(3))) unsigned int*)s, 16, 0, 0);
}

// ---------------- GEMM: C = A[M,K](bf16) * Bt[Ntot,K]^T (bf16), fp32 acc ----------------
__global__ __launch_bounds__(256) void gemm_k(
    const bf16_t* __restrict__ A, int lda, int M,
    const bf16_t* __restrict__ Bt, int K,
    const float* __restrict__ bias, int relu_flag,
    bf16_t* __restrict__ outb, int ldo, int ocol)
{
    __shared__ __align__(16) bf16_t As[BM * BK];   // 8 KB
    __shared__ __align__(16) bf16_t Bs[BN * BK];   // 8 KB
    const int tid  = threadIdx.x;
    const int m0   = blockIdx.x * BM;
    const int n0   = blockIdx.y * BN;
    const int wave = tid >> 6, lane = tid & 63;
    const int wr   = wave >> 1, wc = wave & 1;
    const int lm   = lane & 15, quad = lane >> 4;

    f32x4 acc[4][4] = {};

    for (int k0 = 0; k0 < K; k0 += BK) {
        __syncthreads();
        #pragma unroll
        for (int j = 0; j < 2; j++) {
            int c   = wave * 128 + j * 64 + lane;
            int row = c >> 2;
            int col = (c & 3) << 3;
            int gm  = m0 + row; if (gm >= M) gm = M - 1;   // clamp; stores guarded
            gload_lds16(A + (size_t)gm * lda + k0 + col,
                        As + (size_t)(wave * 128 + j * 64) * 8);
        }
        #pragma unroll
        for (int j = 0; j < 2; j++) {
            int c   = wave * 128 + j * 64 + lane;
            int row = c >> 2;
            int col = (c & 3) << 3;
            gload_lds16(Bt + (size_t)(n0 + row) * K + k0 + col,
                        Bs + (size_t)(wave * 128 + j * 64) * 8);
        }
        __syncthreads();

        bf16x8 af[4], bfr[4];
        #pragma unroll
        for (int i = 0; i < 4; i++)
            af[i] = *(const bf16x8*)&As[(wr * 64 + i * 16 + lm) * BK + quad * 8];
        #pragma unroll
        for (int i = 0; i < 4; i++)
            bfr[i] = *(const bf16x8*)&Bs[(wc * 64 + i * 16 + lm) * BK + quad * 8];
        #pragma unroll
        for (int mi = 0; mi < 4; mi++)
            #pragma unroll
            for (int ni = 0; ni < 4; ni++)
                acc[mi][ni] = __builtin_amdgcn_mfma_f32_16x16x32_bf16(
                    af[mi], bfr[ni], acc[mi][ni], 0, 0, 0);
    }

    #pragma unroll
    for (int mi = 0; mi < 4; mi++) {
        #pragma unroll
        for (int ni = 0; ni < 4; ni++) {
            int col = n0 + wc * 64 + ni * 16 + lm;
            float b = bias[col];
            #pragma unroll
            for (int r = 0; r < 4; r++) {
                int row = m0 + wr * 64 + mi * 16 + quad * 4 + r;
                if (row < M) {
                    float v = acc[mi][ni][r] + b;
                    if (relu_flag) v = fmaxf(v, 0.f);
                    outb[(size_t)row * ldo + ocol + col] = (bf16_t)v;
                }
            }
        }
    }
}

// ---------------- CSR build ----------------
__global__ void count_k(const int* __restrict__ dst, const int* __restrict__ rel,
                        int* __restrict__ cnt, int E)
{
    int e = blockIdx.x * blockDim.x + threadIdx.x;
    if (e < E) atomicAdd(&cnt[dst[e] * 4 + rel[e]], 1);
}

__global__ void scan_partial(const int* __restrict__ cnt, int* __restrict__ offs,
                             int* __restrict__ chunkSums, int NSEG)
{
    __shared__ int sh[256];
    int t = threadIdx.x;
    int idx = blockIdx.x * 256 + t;
    int v = (idx < NSEG) ? cnt[idx] : 0;
    sh[t] = v;
    __syncthreads();
    for (int d = 1; d < 256; d <<= 1) {
        int add = (t >= d) ? sh[t - d] : 0;
        __syncthreads();
        sh[t] += add;
        __syncthreads();
    }
    if (idx < NSEG) offs[idx] = sh[t] - v;
    if (t == 255) chunkSums[blockIdx.x] = sh[t];
}

__global__ void scan_chunks(int* __restrict__ chunkSums, int NCHUNK)
{
    __shared__ int sh[1024];
    int t = threadIdx.x;
    int v = (t < NCHUNK) ? chunkSums[t] : 0;
    sh[t] = v;
    __syncthreads();
    for (int d = 1; d < 1024; d <<= 1) {
        int add = (t >= d) ? sh[t - d] : 0;
        __syncthreads();
        sh[t] += add;
        __syncthreads();
    }
    if (t < NCHUNK) chunkSums[t] = sh[t] - v;
}

__global__ void scan_add(int* __restrict__ offs, const int* __restrict__ chunkSums,
                         int* __restrict__ cursor, int NSEG)
{
    int idx = blockIdx.x * 256 + threadIdx.x;
    if (idx < NSEG) {
        int o = offs[idx] + chunkSums[blockIdx.x];
        offs[idx] = o;
        cursor[idx] = o;
    }
}

__global__ void fill_k(const int* __restrict__ src, const int* __restrict__ dst,
                       const int* __restrict__ rel,
                       int* __restrict__ cursor, int* __restrict__ eidx, int E)
{
    int e = blockIdx.x * blockDim.x + threadIdx.x;
    if (e < E) {
        int seg = dst[e] * 4 + rel[e];
        int pos = atomicAdd(&cursor[seg], 1);
        eidx[pos] = src[e];
    }
}

// ---------------- segment mean, D=256: one wave/segment, 4-deep unrolled gathers ----
__global__ void seg_mean256(const int* __restrict__ offs, const int* __restrict__ cnt,
                            const int* __restrict__ eidx,
                            const bf16_t* __restrict__ xb, int ldx,
                            bf16_t* __restrict__ Aout, int lda, int NSEG)
{
    int wv = (blockIdx.x << 2) + (threadIdx.x >> 6);
    if (wv >= NSEG) return;
    int lane = threadIdx.x & 63;
    int c = lane << 2;                      // 64 lanes x 4 elems = 256 cols
    int start = offs[wv];
    int n = cnt[wv];
    f32x4 acc = {};
    int i = 0;
    for (; i + 4 <= n; i += 4) {
        int s0 = eidx[start + i + 0];
        int s1 = eidx[start + i + 1];
        int s2 = eidx[start + i + 2];
        int s3 = eidx[start + i + 3];
        bf16x4 v0 = *(const bf16x4*)(xb + (size_t)s0 * ldx + c);
        bf16x4 v1 = *(const bf16x4*)(xb + (size_t)s1 * ldx + c);
        bf16x4 v2 = *(const bf16x4*)(xb + (size_t)s2 * ldx + c);
        bf16x4 v3 = *(const bf16x4*)(xb + (size_t)s3 * ldx + c);
        #pragma unroll
        for (int j = 0; j < 4; j++)
            acc[j] += ((float)v0[j] + (float)v1[j]) + ((float)v2[j] + (float)v3[j]);
    }
    for (; i < n; i++) {
        int s = eidx[start + i];
        bf16x4 v = *(const bf16x4*)(xb + (size_t)s * ldx + c);
        #pragma unroll
        for (int j = 0; j < 4; j++) acc[j] += (float)v[j];
    }
    float inv = 1.0f / ((float)n + 1e-10f);
    int node = wv >> 2, r = wv & 3;
    bf16x4 o;
    o[0] = (bf16_t)(acc[0] * inv);
    o[1] = (bf16_t)(acc[1] * inv);
    o[2] = (bf16_t)(acc[2] * inv);
    o[3] = (bf16_t)(acc[3] * inv);
    *(bf16x4*)(Aout + (size_t)node * lda + r * 256 + c) = o;
}

// ---------------- segment mean, D=128: half-wave per edge (2 edges in flight),
// lanes 0-31 cover all 128 cols via bf16x4; cross-half shfl reduce at end ----
__global__ void seg_mean128(const int* __restrict__ offs, const int* __restrict__ cnt,
                            const int* __restrict__ eidx,
                            const bf16_t* __restrict__ xb, int ldx,
                            bf16_t* __restrict__ Aout, int lda, int NSEG)
{
    int wv = (blockIdx.x << 2) + (threadIdx.x >> 6);
    if (wv >= NSEG) return;
    int lane = threadIdx.x & 63;
    int half = lane >> 5;                   // 0: even edge, 1: odd edge
    int c = (lane & 31) << 2;               // 32 lanes x 4 elems = 128 cols
    int start = offs[wv];
    int n = cnt[wv];
    f32x4 acc = {};
    int i = 0;
    for (; i + 4 <= n; i += 4) {            // 4 edges per iter, 2 gathers/half
        int s0 = eidx[start + i + half];
        int s1 = eidx[start + i + 2 + half];
        bf16x4 v0 = *(const bf16x4*)(xb + (size_t)s0 * ldx + c);
        bf16x4 v1 = *(const bf16x4*)(xb + (size_t)s1 * ldx + c);
        #pragma unroll
        for (int j = 0; j < 4; j++) acc[j] += (float)v0[j] + (float)v1[j];
    }
    for (; i + 2 <= n; i += 2) {
        int s = eidx[start + i + half];
        bf16x4 v = *(const bf16x4*)(xb + (size_t)s * ldx + c);
        #pragma unroll
        for (int j = 0; j < 4; j++) acc[j] += (float)v[j];
    }
    if (i < n && half == 0) {               // odd remainder: even half takes it
        int s = eidx[start + i];
        bf16x4 v = *(const bf16x4*)(xb + (size_t)s * ldx + c);
        #pragma unroll
        for (int j = 0; j < 4; j++) acc[j] += (float)v[j];
    }
    #pragma unroll
    for (int j = 0; j < 4; j++) acc[j] += __shfl_xor(acc[j], 32, 64);
    if (half == 0) {
        float inv = 1.0f / ((float)n + 1e-10f);
        int node = wv >> 2, r = wv & 3;
        bf16x4 o;
        o[0] = (bf16_t)(acc[0] * inv);
        o[1] = (bf16_t)(acc[1] * inv);
        o[2] = (bf16_t)(acc[2] * inv);
        o[3] = (bf16_t)(acc[3] * inv);
        *(bf16x4*)(Aout + (size_t)node * lda + r * 128 + c) = o;
    }
}

// x fp32 [N,128] -> bf16 into A1 columns 512..640 (ld 640)
__global__ void convert_x_k(const float* __restrict__ x, bf16_t* __restrict__ A1, int N)
{
    int t = blockIdx.x * blockDim.x + threadIdx.x;
    if (t >= N * 32) return;
    int row = t >> 5;
    int c = (t & 31) << 2;
    f32x4 v = *(const f32x4*)(x + (size_t)row * 128 + c);
    bf16x4 o;
    o[0] = (bf16_t)v[0]; o[1] = (bf16_t)v[1]; o[2] = (bf16_t)v[2]; o[3] = (bf16_t)v[3];
    *(bf16x4*)(A1 + (size_t)row * 640 + 512 + c) = o;
}

// Wt[(n0+n)*ldk + k0 + k] = (bf16) W[k, n];  W is [K,256] row-major
__global__ void transpose_w(const float* __restrict__ W, bf16_t* __restrict__ Wt,
                            int K, int ldk, int k0, int n0)
{
    int t = blockIdx.x * blockDim.x + threadIdx.x;
    if (t >= K * 256) return;
    int k = t >> 8, n = t & 255;
    Wt[(size_t)(n0 + n) * ldk + k0 + k] = (bf16_t)W[(size_t)k * 256 + n];
}

__global__ void prep_bias(const float* rb1, const float* lb1,
                          const float* rb2, const float* lb2,
                          const float* hpb1, const float* htb1,
                          const float* hpb2, const float* htb2,
                          float* bR1, float* bR2, float* bH1, float* bH2)
{
    int t = threadIdx.x;  // 256
    bR1[t] = rb1[t] + lb1[t];
    bR2[t] = rb2[t] + lb2[t];
    bH1[t] = hpb1[t]; bH1[256 + t] = htb1[t];
    bH2[t] = hpb2[t]; bH2[256 + t] = htb2[t];
}

// h' = sigmoid(G)*relu(P) + (1-sigmoid(G))*h ;  PG = [P | G] bf16 [N,512]
__global__ void highway_k(const bf16_t* __restrict__ PG, const bf16_t* __restrict__ h,
                          int N, bf16_t* __restrict__ outb, int ldo, int ocol,
                          float* __restrict__ outf)
{
    int t = blockIdx.x * blockDim.x + threadIdx.x;
    if (t >= N * 64) return;
    int row = t >> 6;
    int c = (t & 63) << 2;
    size_t ip = (size_t)row * 512 + c;
    bf16x4 p = *(const bf16x4*)(PG + ip);
    bf16x4 g = *(const bf16x4*)(PG + ip + 256);
    bf16x4 hv = *(const bf16x4*)(h + (size_t)row * 256 + c);
    bf16x4 ob;
    f32x4 of;
    #pragma unroll
    for (int j = 0; j < 4; j++) {
        float gg = 1.0f / (1.0f + __expf(-(float)g[j]));
        float pp = fmaxf((float)p[j], 0.f);
        float v = gg * pp + (1.0f - gg) * (float)hv[j];
        ob[j] = (bf16_t)v;
        of[j] = v;
    }
    if (outb) *(bf16x4*)(outb + (size_t)row * ldo + ocol + c) = ob;
    if (outf) *(f32x4*)(outf + (size_t)row * 256 + c) = of;
}

extern "C" void kernel_launch(void* const* d_in, const int* in_sizes, int n_in,
                              void* d_out, int out_size, void* d_ws, size_t ws_size,
                              hipStream_t stream)
{
    const float* x       = (const float*)d_in[0];
    const int*   src     = (const int*)d_in[1];
    const int*   dst     = (const int*)d_in[2];
    const int*   rel     = (const int*)d_in[3];
    const float* rel_w1  = (const float*)d_in[4];
    const float* rel_b1  = (const float*)d_in[5];
    const float* loop_w1 = (const float*)d_in[6];
    const float* loop_b1 = (const float*)d_in[7];
    const float* hp_w1   = (const float*)d_in[8];
    const float* hp_b1   = (const float*)d_in[9];
    const float* ht_w1   = (const float*)d_in[10];
    const float* ht_b1   = (const float*)d_in[11];
    const float* rel_w2  = (const float*)d_in[12];
    const float* rel_b2  = (const float*)d_in[13];
    const float* loop_w2 = (const float*)d_in[14];
    const float* loop_b2 = (const float*)d_in[15];
    const float* hp_w2   = (const float*)d_in[16];
    const float* hp_b2   = (const float*)d_in[17];
    const float* ht_w2   = (const float*)d_in[18];
    const float* ht_b2   = (const float*)d_in[19];

    const int N = in_sizes[0] / 128;   // 50000
    const int E = in_sizes[1];         // 800000
    const int NSEG = N * 4;            // 200000
    const int NCHUNK = (NSEG + 255) / 256;   // 782
    float* out = (float*)d_out;

    char* ws = (char*)d_ws;
    size_t off = 0;
    auto alloc = [&](size_t bytes) {
        void* p = ws + off;
        off += (bytes + 255) & ~(size_t)255;
        return p;
    };
    int*    cnt    = (int*)alloc((size_t)NSEG * 4);
    int*    offs   = (int*)alloc((size_t)NSEG * 4);
    int*    cursor = (int*)alloc((size_t)NSEG * 4);
    int*    chunkS = (int*)alloc(4096);
    int*    eidx   = (int*)alloc((size_t)E * 4);
    bf16_t* A1     = (bf16_t*)alloc((size_t)N * 640 * 2);
    bf16_t* A2     = (bf16_t*)alloc((size_t)N * 1280 * 2);
    bf16_t* h      = (bf16_t*)alloc((size_t)N * 256 * 2);
    bf16_t* W1t    = (bf16_t*)alloc((size_t)256 * 640 * 2);
    bf16_t* W2t    = (bf16_t*)alloc((size_t)256 * 1280 * 2);
    bf16_t* Wh1t   = (bf16_t*)alloc((size_t)512 * 256 * 2);
    bf16_t* Wh2t   = (bf16_t*)alloc((size_t)512 * 256 * 2);
    float*  bR1    = (float*)alloc(256 * 4);
    float*  bR2    = (float*)alloc(256 * 4);
    float*  bH1    = (float*)alloc(512 * 4);
    float*  bH2    = (float*)alloc(512 * 4);
    bf16_t* PG     = A1;   // alias: A1 dead after layer-1 RGC GEMM

    dim3 blk(256);
    const int mtiles = (N + BM - 1) / BM;    // 391

    // ---- weight/bias prep ----
    transpose_w<<<dim3(512), blk, 0, stream>>>(rel_w1, W1t, 512, 640, 0, 0);
    transpose_w<<<dim3(128), blk, 0, stream>>>(loop_w1, W1t, 128, 640, 512, 0);
    transpose_w<<<dim3(1024), blk, 0, stream>>>(rel_w2, W2t, 1024, 1280, 0, 0);
    transpose_w<<<dim3(256), blk, 0, stream>>>(loop_w2, W2t, 256, 1280, 1024, 0);
    transpose_w<<<dim3(256), blk, 0, stream>>>(hp_w1, Wh1t, 256, 256, 0, 0);
    transpose_w<<<dim3(256), blk, 0, stream>>>(ht_w1, Wh1t, 256, 256, 0, 256);
    transpose_w<<<dim3(256), blk, 0, stream>>>(hp_w2, Wh2t, 256, 256, 0, 0);
    transpose_w<<<dim3(256), blk, 0, stream>>>(ht_w2, Wh2t, 256, 256, 0, 256);
    prep_bias<<<dim3(1), blk, 0, stream>>>(rel_b1, loop_b1, rel_b2, loop_b2,
                                           hp_b1, ht_b1, hp_b2, ht_b2,
                                           bR1, bR2, bH1, bH2);
    convert_x_k<<<dim3((N * 32 + 255) / 256), blk, 0, stream>>>(x, A1, N);

    // ---- CSR build (shared by both layers) ----
    hipMemsetAsync(cnt, 0, (size_t)NSEG * 4, stream);
    count_k<<<dim3((E + 255) / 256), blk, 0, stream>>>(dst, rel, cnt, E);
    scan_partial<<<dim3(NCHUNK), blk, 0, stream>>>(cnt, offs, chunkS, NSEG);
    scan_chunks<<<dim3(1), dim3(1024), 0, stream>>>(chunkS, NCHUNK);
    scan_add<<<dim3(NCHUNK), blk, 0, stream>>>(offs, chunkS, cursor, NSEG);
    fill_k<<<dim3((E + 255) / 256), blk, 0, stream>>>(src, dst, rel, cursor, eidx, E);

    // ---- layer 1 ----
    seg_mean128<<<dim3((NSEG + 3) / 4), blk, 0, stream>>>(offs, cnt, eidx,
                                                          A1 + 512, 640, A1, 640, NSEG);
    gemm_k<<<dim3(mtiles, 2), blk, 0, stream>>>(A1, 640, N, W1t, 640,
                                                bR1, 1, h, 256, 0);
    gemm_k<<<dim3(mtiles, 4), blk, 0, stream>>>(h, 256, N, Wh1t, 256,
                                                bH1, 0, PG, 512, 0);
    highway_k<<<dim3((N * 64 + 255) / 256), blk, 0, stream>>>(PG, h, N,
                                                              A2, 1280, 1024, nullptr);

    // ---- layer 2 ----
    seg_mean256<<<dim3((NSEG + 3) / 4), blk, 0, stream>>>(offs, cnt, eidx,
                                                          A2 + 1024, 1280, A2, 1280, NSEG);
    gemm_k<<<dim3(mtiles, 2), blk, 0, stream>>>(A2, 1280, N, W2t, 1280,
                                                bR2, 1, h, 256, 0);
    gemm_k<<<dim3(mtiles, 4), blk, 0, stream>>>(h, 256, N, Wh2t, 256,
                                                bH2, 0, PG, 512, 0);
    highway_k<<<dim3((N * 64 + 255) / 256), blk, 0, stream>>>(PG, h, N,
                                                              nullptr, 0, 0, out);
}

// Round 5
// 582.106 us; speedup vs baseline: 1.5644x; 1.0590x over previous
//
#include <hip/hip_runtime.h>

typedef __bf16 bf16_t;
typedef __bf16 bf16x8 __attribute__((ext_vector_type(8)));
typedef __bf16 bf16x4 __attribute__((ext_vector_type(4)));
typedef float f32x4 __attribute__((ext_vector_type(4)));

#define BM 128
#define BN 128
#define BK 64
// LDS layout: per row of 8 x 16B chunks, chunk cc is stored at slot (cc ^ (row&7)).
// The DMA writes base + lane*16 contiguously (m104/m108), so we permute WHICH
// global chunk each lane loads; fragment reads then hit all 32 banks (2-way max).

__device__ __forceinline__ void gload_lds16(const void* g, void* s) {
    __builtin_amdgcn_global_load_lds(
        (const __attribute__((address_space(1))) unsigned int*)g,
        (__attribute__((address_space(3))) unsigned int*)s, 16, 0, 0);
}

// ---------------- GEMM: C = A[M,K](bf16) * Bt[Ntot,K]^T (bf16), fp32 acc ----------------
// Grid: 1-D, size supers*8*NTN where supers=ceil(NTM/8). Decode puts the NTN
// n-tiles of one m-tile at linear IDs 8 apart -> same XCD (L2 A-tile reuse).
__global__ __launch_bounds__(256) void gemm_k(
    const bf16_t* __restrict__ A, int lda, int M,
    const bf16_t* __restrict__ Bt, int K,
    const float* __restrict__ bias, int relu_flag,
    bf16_t* __restrict__ outb, int ldo, int ocol,
    int NTM, int NTN)
{
    __shared__ __align__(16) bf16_t As[BM * BK];   // 16 KB
    __shared__ __align__(16) bf16_t Bs[BN * BK];   // 16 KB

    const int L    = blockIdx.x;
    const int xcd  = L & 7;
    const int rest = L >> 3;
    const int nt   = rest % NTN;
    const int sup  = rest / NTN;
    const int mt   = sup * 8 + xcd;
    if (mt >= NTM) return;
    const int m0 = mt * BM;
    const int n0 = nt * BN;

    const int tid  = threadIdx.x;
    const int wave = tid >> 6, lane = tid & 63;
    const int wr   = wave >> 1, wc = wave & 1;
    const int lm   = lane & 15, quad = lane >> 4;

    // per-lane global pointers for 4 A-chunks + 4 B-chunks (bank-swizzled cc)
    const bf16_t* ag[4];
    const bf16_t* bg[4];
    #pragma unroll
    for (int j = 0; j < 4; j++) {
        int c    = wave * 256 + j * 64 + lane;   // chunk slot 0..1023
        int row  = c >> 3;
        int cc   = (c & 7) ^ (row & 7);          // swizzled global chunk
        int col  = cc << 3;                      // element offset in K-tile
        int gm   = m0 + row; if (gm >= M) gm = M - 1;   // clamp; stores guarded
        ag[j] = A  + (size_t)gm * lda + col;
        bg[j] = Bt + (size_t)(n0 + row) * K + col;
    }

    f32x4 acc[4][4] = {};

    for (int k0 = 0; k0 < K; k0 += BK) {
        __syncthreads();
        #pragma unroll
        for (int j = 0; j < 4; j++)
            gload_lds16(ag[j] + k0, As + (size_t)(wave * 256 + j * 64) * 8);
        #pragma unroll
        for (int j = 0; j < 4; j++)
            gload_lds16(bg[j] + k0, Bs + (size_t)(wave * 256 + j * 64) * 8);
        __syncthreads();

        #pragma unroll
        for (int h = 0; h < 2; h++) {
            bf16x8 af[4], bfr[4];
            #pragma unroll
            for (int i = 0; i < 4; i++) {
                int r = wr * 64 + i * 16 + lm;
                af[i] = *(const bf16x8*)&As[(size_t)(r * 8 + ((h * 4 + quad) ^ (r & 7))) * 8];
            }
            #pragma unroll
            for (int i = 0; i < 4; i++) {
                int r = wc * 64 + i * 16 + lm;
                bfr[i] = *(const bf16x8*)&Bs[(size_t)(r * 8 + ((h * 4 + quad) ^ (r & 7))) * 8];
            }
            #pragma unroll
            for (int mi = 0; mi < 4; mi++)
                #pragma unroll
                for (int ni = 0; ni < 4; ni++)
                    acc[mi][ni] = __builtin_amdgcn_mfma_f32_16x16x32_bf16(
                        af[mi], bfr[ni], acc[mi][ni], 0, 0, 0);
        }
    }

    // epilogue: C/D layout col=lane&15, row=quad*4+r
    #pragma unroll
    for (int mi = 0; mi < 4; mi++) {
        #pragma unroll
        for (int ni = 0; ni < 4; ni++) {
            int col = n0 + wc * 64 + ni * 16 + lm;
            float b = bias[col];
            #pragma unroll
            for (int r = 0; r < 4; r++) {
                int row = m0 + wr * 64 + mi * 16 + quad * 4 + r;
                if (row < M) {
                    float v = acc[mi][ni][r] + b;
                    if (relu_flag) v = fmaxf(v, 0.f);
                    outb[(size_t)row * ldo + ocol + col] = (bf16_t)v;
                }
            }
        }
    }
}

// ---------------- CSR build ----------------
__global__ void count_k(const int* __restrict__ dst, const int* __restrict__ rel,
                        int* __restrict__ cnt, int E)
{
    int e = blockIdx.x * blockDim.x + threadIdx.x;
    if (e < E) atomicAdd(&cnt[dst[e] * 4 + rel[e]], 1);
}

__global__ void scan_partial(const int* __restrict__ cnt, int* __restrict__ offs,
                             int* __restrict__ chunkSums, int NSEG)
{
    __shared__ int sh[256];
    int t = threadIdx.x;
    int idx = blockIdx.x * 256 + t;
    int v = (idx < NSEG) ? cnt[idx] : 0;
    sh[t] = v;
    __syncthreads();
    for (int d = 1; d < 256; d <<= 1) {
        int add = (t >= d) ? sh[t - d] : 0;
        __syncthreads();
        sh[t] += add;
        __syncthreads();
    }
    if (idx < NSEG) offs[idx] = sh[t] - v;
    if (t == 255) chunkSums[blockIdx.x] = sh[t];
}

__global__ void scan_chunks(int* __restrict__ chunkSums, int NCHUNK)
{
    __shared__ int sh[1024];
    int t = threadIdx.x;
    int v = (t < NCHUNK) ? chunkSums[t] : 0;
    sh[t] = v;
    __syncthreads();
    for (int d = 1; d < 1024; d <<= 1) {
        int add = (t >= d) ? sh[t - d] : 0;
        __syncthreads();
        sh[t] += add;
        __syncthreads();
    }
    if (t < NCHUNK) chunkSums[t] = sh[t] - v;
}

__global__ void scan_add(int* __restrict__ offs, const int* __restrict__ chunkSums,
                         int* __restrict__ cursor, int NSEG)
{
    int idx = blockIdx.x * 256 + threadIdx.x;
    if (idx < NSEG) {
        int o = offs[idx] + chunkSums[blockIdx.x];
        offs[idx] = o;
        cursor[idx] = o;
    }
}

__global__ void fill_k(const int* __restrict__ src, const int* __restrict__ dst,
                       const int* __restrict__ rel,
                       int* __restrict__ cursor, int* __restrict__ eidx, int E)
{
    int e = blockIdx.x * blockDim.x + threadIdx.x;
    if (e < E) {
        int seg = dst[e] * 4 + rel[e];
        int pos = atomicAdd(&cursor[seg], 1);
        eidx[pos] = src[e];
    }
}

// ---------------- segment mean, D=256: one wave/segment, 4-deep unrolled gathers ----
__global__ void seg_mean256(const int* __restrict__ offs, const int* __restrict__ cnt,
                            const int* __restrict__ eidx,
                            const bf16_t* __restrict__ xb, int ldx,
                            bf16_t* __restrict__ Aout, int lda, int NSEG)
{
    int wv = (blockIdx.x << 2) + (threadIdx.x >> 6);
    if (wv >= NSEG) return;
    int lane = threadIdx.x & 63;
    int c = lane << 2;
    int start = offs[wv];
    int n = cnt[wv];
    f32x4 acc = {};
    int i = 0;
    for (; i + 4 <= n; i += 4) {
        int s0 = eidx[start + i + 0];
        int s1 = eidx[start + i + 1];
        int s2 = eidx[start + i + 2];
        int s3 = eidx[start + i + 3];
        bf16x4 v0 = *(const bf16x4*)(xb + (size_t)s0 * ldx + c);
        bf16x4 v1 = *(const bf16x4*)(xb + (size_t)s1 * ldx + c);
        bf16x4 v2 = *(const bf16x4*)(xb + (size_t)s2 * ldx + c);
        bf16x4 v3 = *(const bf16x4*)(xb + (size_t)s3 * ldx + c);
        #pragma unroll
        for (int j = 0; j < 4; j++)
            acc[j] += ((float)v0[j] + (float)v1[j]) + ((float)v2[j] + (float)v3[j]);
    }
    for (; i < n; i++) {
        int s = eidx[start + i];
        bf16x4 v = *(const bf16x4*)(xb + (size_t)s * ldx + c);
        #pragma unroll
        for (int j = 0; j < 4; j++) acc[j] += (float)v[j];
    }
    float inv = 1.0f / ((float)n + 1e-10f);
    int node = wv >> 2, r = wv & 3;
    bf16x4 o;
    o[0] = (bf16_t)(acc[0] * inv);
    o[1] = (bf16_t)(acc[1] * inv);
    o[2] = (bf16_t)(acc[2] * inv);
    o[3] = (bf16_t)(acc[3] * inv);
    *(bf16x4*)(Aout + (size_t)node * lda + r * 256 + c) = o;
}

// ---------------- segment mean, D=128: half-wave per edge ----------------
__global__ void seg_mean128(const int* __restrict__ offs, const int* __restrict__ cnt,
                            const int* __restrict__ eidx,
                            const bf16_t* __restrict__ xb, int ldx,
                            bf16_t* __restrict__ Aout, int lda, int NSEG)
{
    int wv = (blockIdx.x << 2) + (threadIdx.x >> 6);
    if (wv >= NSEG) return;
    int lane = threadIdx.x & 63;
    int half = lane >> 5;
    int c = (lane & 31) << 2;
    int start = offs[wv];
    int n = cnt[wv];
    f32x4 acc = {};
    int i = 0;
    for (; i + 4 <= n; i += 4) {
        int s0 = eidx[start + i + half];
        int s1 = eidx[start + i + 2 + half];
        bf16x4 v0 = *(const bf16x4*)(xb + (size_t)s0 * ldx + c);
        bf16x4 v1 = *(const bf16x4*)(xb + (size_t)s1 * ldx + c);
        #pragma unroll
        for (int j = 0; j < 4; j++) acc[j] += (float)v0[j] + (float)v1[j];
    }
    for (; i + 2 <= n; i += 2) {
        int s = eidx[start + i + half];
        bf16x4 v = *(const bf16x4*)(xb + (size_t)s * ldx + c);
        #pragma unroll
        for (int j = 0; j < 4; j++) acc[j] += (float)v[j];
    }
    if (i < n && half == 0) {
        int s = eidx[start + i];
        bf16x4 v = *(const bf16x4*)(xb + (size_t)s * ldx + c);
        #pragma unroll
        for (int j = 0; j < 4; j++) acc[j] += (float)v[j];
    }
    #pragma unroll
    for (int j = 0; j < 4; j++) acc[j] += __shfl_xor(acc[j], 32, 64);
    if (half == 0) {
        float inv = 1.0f / ((float)n + 1e-10f);
        int node = wv >> 2, r = wv & 3;
        bf16x4 o;
        o[0] = (bf16_t)(acc[0] * inv);
        o[1] = (bf16_t)(acc[1] * inv);
        o[2] = (bf16_t)(acc[2] * inv);
        o[3] = (bf16_t)(acc[3] * inv);
        *(bf16x4*)(Aout + (size_t)node * lda + r * 128 + c) = o;
    }
}

// x fp32 [N,128] -> bf16 into A1 columns 512..640 (ld 640)
__global__ void convert_x_k(const float* __restrict__ x, bf16_t* __restrict__ A1, int N)
{
    int t = blockIdx.x * blockDim.x + threadIdx.x;
    if (t >= N * 32) return;
    int row = t >> 5;
    int c = (t & 31) << 2;
    f32x4 v = *(const f32x4*)(x + (size_t)row * 128 + c);
    bf16x4 o;
    o[0] = (bf16_t)v[0]; o[1] = (bf16_t)v[1]; o[2] = (bf16_t)v[2]; o[3] = (bf16_t)v[3];
    *(bf16x4*)(A1 + (size_t)row * 640 + 512 + c) = o;
}

// Wt[(n0+n)*ldk + k0 + k] = (bf16) W[k, n];  W is [K,256] row-major
__global__ void transpose_w(const float* __restrict__ W, bf16_t* __restrict__ Wt,
                            int K, int ldk, int k0, int n0)
{
    int t = blockIdx.x * blockDim.x + threadIdx.x;
    if (t >= K * 256) return;
    int k = t >> 8, n = t & 255;
    Wt[(size_t)(n0 + n) * ldk + k0 + k] = (bf16_t)W[(size_t)k * 256 + n];
}

__global__ void prep_bias(const float* rb1, const float* lb1,
                          const float* rb2, const float* lb2,
                          const float* hpb1, const float* htb1,
                          const float* hpb2, const float* htb2,
                          float* bR1, float* bR2, float* bH1, float* bH2)
{
    int t = threadIdx.x;  // 256
    bR1[t] = rb1[t] + lb1[t];
    bR2[t] = rb2[t] + lb2[t];
    bH1[t] = hpb1[t]; bH1[256 + t] = htb1[t];
    bH2[t] = hpb2[t]; bH2[256 + t] = htb2[t];
}

// h' = sigmoid(G)*relu(P) + (1-sigmoid(G))*h ;  PG = [P | G] bf16 [N,512]
__global__ void highway_k(const bf16_t* __restrict__ PG, const bf16_t* __restrict__ h,
                          int N, bf16_t* __restrict__ outb, int ldo, int ocol,
                          float* __restrict__ outf)
{
    int t = blockIdx.x * blockDim.x + threadIdx.x;
    if (t >= N * 64) return;
    int row = t >> 6;
    int c = (t & 63) << 2;
    size_t ip = (size_t)row * 512 + c;
    bf16x4 p = *(const bf16x4*)(PG + ip);
    bf16x4 g = *(const bf16x4*)(PG + ip + 256);
    bf16x4 hv = *(const bf16x4*)(h + (size_t)row * 256 + c);
    bf16x4 ob;
    f32x4 of;
    #pragma unroll
    for (int j = 0; j < 4; j++) {
        float gg = 1.0f / (1.0f + __expf(-(float)g[j]));
        float pp = fmaxf((float)p[j], 0.f);
        float v = gg * pp + (1.0f - gg) * (float)hv[j];
        ob[j] = (bf16_t)v;
        of[j] = v;
    }
    if (outb) *(bf16x4*)(outb + (size_t)row * ldo + ocol + c) = ob;
    if (outf) *(f32x4*)(outf + (size_t)row * 256 + c) = of;
}

extern "C" void kernel_launch(void* const* d_in, const int* in_sizes, int n_in,
                              void* d_out, int out_size, void* d_ws, size_t ws_size,
                              hipStream_t stream)
{
    const float* x       = (const float*)d_in[0];
    const int*   src     = (const int*)d_in[1];
    const int*   dst     = (const int*)d_in[2];
    const int*   rel     = (const int*)d_in[3];
    const float* rel_w1  = (const float*)d_in[4];
    const float* rel_b1  = (const float*)d_in[5];
    const float* loop_w1 = (const float*)d_in[6];
    const float* loop_b1 = (const float*)d_in[7];
    const float* hp_w1   = (const float*)d_in[8];
    const float* hp_b1   = (const float*)d_in[9];
    const float* ht_w1   = (const float*)d_in[10];
    const float* ht_b1   = (const float*)d_in[11];
    const float* rel_w2  = (const float*)d_in[12];
    const float* rel_b2  = (const float*)d_in[13];
    const float* loop_w2 = (const float*)d_in[14];
    const float* loop_b2 = (const float*)d_in[15];
    const float* hp_w2   = (const float*)d_in[16];
    const float* hp_b2   = (const float*)d_in[17];
    const float* ht_w2   = (const float*)d_in[18];
    const float* ht_b2   = (const float*)d_in[19];

    const int N = in_sizes[0] / 128;   // 50000
    const int E = in_sizes[1];         // 800000
    const int NSEG = N * 4;            // 200000
    const int NCHUNK = (NSEG + 255) / 256;   // 782
    float* out = (float*)d_out;

    char* ws = (char*)d_ws;
    size_t off = 0;
    auto alloc = [&](size_t bytes) {
        void* p = ws + off;
        off += (bytes + 255) & ~(size_t)255;
        return p;
    };
    int*    cnt    = (int*)alloc((size_t)NSEG * 4);
    int*    offs   = (int*)alloc((size_t)NSEG * 4);
    int*    cursor = (int*)alloc((size_t)NSEG * 4);
    int*    chunkS = (int*)alloc(4096);
    int*    eidx   = (int*)alloc((size_t)E * 4);
    bf16_t* A1     = (bf16_t*)alloc((size_t)N * 640 * 2);
    bf16_t* A2     = (bf16_t*)alloc((size_t)N * 1280 * 2);
    bf16_t* h      = (bf16_t*)alloc((size_t)N * 256 * 2);
    bf16_t* W1t    = (bf16_t*)alloc((size_t)256 * 640 * 2);
    bf16_t* W2t    = (bf16_t*)alloc((size_t)256 * 1280 * 2);
    bf16_t* Wh1t   = (bf16_t*)alloc((size_t)512 * 256 * 2);
    bf16_t* Wh2t   = (bf16_t*)alloc((size_t)512 * 256 * 2);
    float*  bR1    = (float*)alloc(256 * 4);
    float*  bR2    = (float*)alloc(256 * 4);
    float*  bH1    = (float*)alloc(512 * 4);
    float*  bH2    = (float*)alloc(512 * 4);
    bf16_t* PG     = A1;   // alias: A1 dead after layer-1 RGC GEMM

    dim3 blk(256);
    const int NTM = (N + BM - 1) / BM;       // 391
    const int supers = (NTM + 7) / 8;        // 49
    const int gridRGC = supers * 8 * 2;      // 784
    const int gridHW  = supers * 8 * 4;      // 1568

    // ---- weight/bias prep ----
    transpose_w<<<dim3(512), blk, 0, stream>>>(rel_w1, W1t, 512, 640, 0, 0);
    transpose_w<<<dim3(128), blk, 0, stream>>>(loop_w1, W1t, 128, 640, 512, 0);
    transpose_w<<<dim3(1024), blk, 0, stream>>>(rel_w2, W2t, 1024, 1280, 0, 0);
    transpose_w<<<dim3(256), blk, 0, stream>>>(loop_w2, W2t, 256, 1280, 1024, 0);
    transpose_w<<<dim3(256), blk, 0, stream>>>(hp_w1, Wh1t, 256, 256, 0, 0);
    transpose_w<<<dim3(256), blk, 0, stream>>>(ht_w1, Wh1t, 256, 256, 0, 256);
    transpose_w<<<dim3(256), blk, 0, stream>>>(hp_w2, Wh2t, 256, 256, 0, 0);
    transpose_w<<<dim3(256), blk, 0, stream>>>(ht_w2, Wh2t, 256, 256, 0, 256);
    prep_bias<<<dim3(1), blk, 0, stream>>>(rel_b1, loop_b1, rel_b2, loop_b2,
                                           hp_b1, ht_b1, hp_b2, ht_b2,
                                           bR1, bR2, bH1, bH2);
    convert_x_k<<<dim3((N * 32 + 255) / 256), blk, 0, stream>>>(x, A1, N);

    // ---- CSR build (shared by both layers) ----
    hipMemsetAsync(cnt, 0, (size_t)NSEG * 4, stream);
    count_k<<<dim3((E + 255) / 256), blk, 0, stream>>>(dst, rel, cnt, E);
    scan_partial<<<dim3(NCHUNK), blk, 0, stream>>>(cnt, offs, chunkS, NSEG);
    scan_chunks<<<dim3(1), dim3(1024), 0, stream>>>(chunkS, NCHUNK);
    scan_add<<<dim3(NCHUNK), blk, 0, stream>>>(offs, chunkS, cursor, NSEG);
    fill_k<<<dim3((E + 255) / 256), blk, 0, stream>>>(src, dst, rel, cursor, eidx, E);

    // ---- layer 1 ----
    seg_mean128<<<dim3((NSEG + 3) / 4), blk, 0, stream>>>(offs, cnt, eidx,
                                                          A1 + 512, 640, A1, 640, NSEG);
    gemm_k<<<dim3(gridRGC), blk, 0, stream>>>(A1, 640, N, W1t, 640,
                                              bR1, 1, h, 256, 0, NTM, 2);
    gemm_k<<<dim3(gridHW), blk, 0, stream>>>(h, 256, N, Wh1t, 256,
                                             bH1, 0, PG, 512, 0, NTM, 4);
    highway_k<<<dim3((N * 64 + 255) / 256), blk, 0, stream>>>(PG, h, N,
                                                              A2, 1280, 1024, nullptr);

    // ---- layer 2 ----
    seg_mean256<<<dim3((NSEG + 3) / 4), blk, 0, stream>>>(offs, cnt, eidx,
                                                          A2 + 1024, 1280, A2, 1280, NSEG);
    gemm_k<<<dim3(gridRGC), blk, 0, stream>>>(A2, 1280, N, W2t, 1280,
                                              bR2, 1, h, 256, 0, NTM, 2);
    gemm_k<<<dim3(gridHW), blk, 0, stream>>>(h, 256, N, Wh2t, 256,
                                             bH2, 0, PG, 512, 0, NTM, 4);
    highway_k<<<dim3((N * 64 + 255) / 256), blk, 0, stream>>>(PG, h, N,
                                                              nullptr, 0, 0, out);
}